// Round 3
// baseline (360.532 us; speedup 1.0000x reference)
//
#include <hip/hip_runtime.h>

constexpr int NN = 100000;   // nodes
constexpr int NE = 1600000;  // edges
constexpr int NF = 64;       // input features
constexpr int NH = 16;       // hidden

constexpr int NPB  = 128;                      // nodes per bucket (pow2: dst>>7 / dst&127)
constexpr int NBKT = (NN + NPB - 1) / NPB;     // 782 buckets
constexpr int CAP  = 2560;                     // per-bucket edge capacity (mean 2046, +11 sigma)
constexpr int CHUNK = 8192;                    // edges per block in bucket build
constexpr int NBLK_B = (NE + CHUNK - 1) / CHUNK; // 196

// Kernel 1: per node n: p[n,:] = x[n,:] @ Wl1 ; r[n,:] = x[n,:] @ Wr1
__global__ __launch_bounds__(256)
void k1_node_lin(const float* __restrict__ x,
                 const float* __restrict__ Wl1,
                 const float* __restrict__ Wr1,
                 float* __restrict__ p,
                 float* __restrict__ r)
{
    __shared__ float sW[2 * NF * NH];
    for (int i = threadIdx.x; i < NF * NH; i += 256) {
        sW[i]           = Wl1[i];
        sW[NF * NH + i] = Wr1[i];
    }
    __syncthreads();

    int n = blockIdx.x * 256 + threadIdx.x;
    if (n >= NN) return;

    float aL[NH], aR[NH];
#pragma unroll
    for (int j = 0; j < NH; ++j) { aL[j] = 0.f; aR[j] = 0.f; }

    const float4* xr = reinterpret_cast<const float4*>(x + (size_t)n * NF);
#pragma unroll
    for (int k4 = 0; k4 < NF / 4; ++k4) {
        float4 v = xr[k4];
        float xs[4] = {v.x, v.y, v.z, v.w};
#pragma unroll
        for (int t = 0; t < 4; ++t) {
            const float* wl = &sW[(k4 * 4 + t) * NH];
            const float* wr = &sW[NF * NH + (k4 * 4 + t) * NH];
#pragma unroll
            for (int j = 0; j < NH; ++j) {
                aL[j] = fmaf(xs[t], wl[j], aL[j]);
                aR[j] = fmaf(xs[t], wr[j], aR[j]);
            }
        }
    }

    float4* pp = reinterpret_cast<float4*>(p + (size_t)n * NH);
    float4* rp = reinterpret_cast<float4*>(r + (size_t)n * NH);
#pragma unroll
    for (int j4 = 0; j4 < NH / 4; ++j4) {
        pp[j4] = make_float4(aL[j4*4], aL[j4*4+1], aL[j4*4+2], aL[j4*4+3]);
        rp[j4] = make_float4(aR[j4*4], aR[j4*4+1], aR[j4*4+2], aR[j4*4+3]);
    }
}

// Bucket build: two-pass per block (LDS count -> one global reserve per
// (block,bucket) -> place). Appends fill bucket tails sequentially, so HBM
// write-back ~= payload, not 64B per scattered 4B write.
__global__ __launch_bounds__(256)
void k_bucket(const int* __restrict__ ei, const float* __restrict__ As,
              const float* __restrict__ ws,
              int* __restrict__ bcnt, unsigned int* __restrict__ bmem)
{
    __shared__ int lcnt[NBKT];
    __shared__ int lbase[NBKT];
    int tid = threadIdx.x;
    for (int i = tid; i < NBKT; i += 256) lcnt[i] = 0;
    __syncthreads();

    int base = blockIdx.x * CHUNK;
    float w0 = ws[0], w1 = ws[1];

    // pass A: count kept edges per bucket
    for (int j = 0; j < CHUNK / 256; ++j) {
        int e = base + j * 256 + tid;
        if (e < NE) {
            float ewm = w0 * As[e] + w1 * As[NE + e];
            if (ewm != 0.f)
                atomicAdd(&lcnt[ei[NE + e] >> 7], 1);
        }
    }
    __syncthreads();

    // reserve contiguous ranges in each bucket (one global atomic per nonzero bucket)
    for (int i = tid; i < NBKT; i += 256) {
        int c = lcnt[i];
        lbase[i] = c ? atomicAdd(&bcnt[i], c) : 0;
    }
    __syncthreads();
    for (int i = tid; i < NBKT; i += 256) lcnt[i] = 0;
    __syncthreads();

    // pass B: place (chunk data is L2-hot from pass A)
    for (int j = 0; j < CHUNK / 256; ++j) {
        int e = base + j * 256 + tid;
        if (e < NE) {
            float ewm = w0 * As[e] + w1 * As[NE + e];
            if (ewm != 0.f) {
                int dst = ei[NE + e];
                int b   = dst >> 7;
                int rank = atomicAdd(&lcnt[b], 1);
                bmem[(size_t)b * CAP + lbase[b] + rank] =
                    ((unsigned)ei[e] << 7) | (unsigned)(dst & 127);
            }
        }
    }
}

// Layer-1 aggregation: one block per bucket; LDS accumulator (no global
// atomics); 16 lanes per edge read p[src] as one coalesced 64B line.
// Fused epilogue: h = relu(agg + r + bl1); q = h.Wl2; out = h.Wr2 + bl2.
__global__ __launch_bounds__(256)
void k_agg1(const int* __restrict__ bcnt, const unsigned int* __restrict__ bmem,
            const float* __restrict__ p, const float* __restrict__ r,
            const float* __restrict__ bl1, const float* __restrict__ Wl2,
            const float* __restrict__ bl2, const float* __restrict__ Wr2,
            float* __restrict__ q, float* __restrict__ out)
{
    __shared__ float sagg[NPB * NH];   // 8 KB
    int b = blockIdx.x;
    int tid = threadIdx.x;
    for (int i = tid; i < NPB * NH; i += 256) sagg[i] = 0.f;
    __syncthreads();

    int cnt = bcnt[b];
    int grp = tid >> 4, k = tid & 15;
    const unsigned int* bm = bmem + (size_t)b * CAP;
    for (int i = grp; i < cnt; i += 16) {
        unsigned v = bm[i];               // 16 lanes same addr -> broadcast
        int src = v >> 7;
        int dl  = v & 127;
        atomicAdd(&sagg[dl * NH + k], p[(size_t)src * NH + k]);  // ds_add_f32
    }
    __syncthreads();

    int n0 = b * NPB;
    int nn = min(NPB, NN - n0);
    for (int item = tid; item < nn * NH; item += 256) {
        int l  = item >> 4;
        int kk = item & 15;               // == tid & 15 (stride 256 preserves it)
        float h = sagg[item] + r[(size_t)(n0 + l) * NH + kk] + bl1[kk];
        h = h > 0.f ? h : 0.f;
        float qv = h * Wl2[kk];
        float sv = h * Wr2[kk];
#pragma unroll
        for (int m = 8; m >= 1; m >>= 1) {
            qv += __shfl_xor(qv, m);
            sv += __shfl_xor(sv, m);
        }
        if (kk == 0) {
            q[n0 + l]   = qv;
            out[n0 + l] = sv + bl2[0];
        }
    }
}

// Layer-2 aggregation: same bucket list; LDS scalar accumulation of q[src].
__global__ __launch_bounds__(256)
void k_agg2(const int* __restrict__ bcnt, const unsigned int* __restrict__ bmem,
            const float* __restrict__ q, float* __restrict__ out)
{
    __shared__ float sq[NPB];
    int b = blockIdx.x, tid = threadIdx.x;
    if (tid < NPB) sq[tid] = 0.f;
    __syncthreads();

    int cnt = bcnt[b];
    const unsigned int* bm = bmem + (size_t)b * CAP;
    for (int i = tid; i < cnt; i += 256) {
        unsigned v = bm[i];
        atomicAdd(&sq[v & 127], q[v >> 7]);   // q is 400 KB, L2-resident
    }
    __syncthreads();

    int n0 = b * NPB;
    int nn = min(NPB, NN - n0);
    if (tid < nn) out[n0 + tid] += sq[tid];
}

extern "C" void kernel_launch(void* const* d_in, const int* in_sizes, int n_in,
                              void* d_out, int out_size, void* d_ws, size_t ws_size,
                              hipStream_t stream)
{
    const float* x   = (const float*)d_in[0];
    const int*   ei  = (const int*)  d_in[1];
    const float* As  = (const float*)d_in[2];
    const float* ws  = (const float*)d_in[3];
    const float* Wl1 = (const float*)d_in[4];
    const float* bl1 = (const float*)d_in[5];
    const float* Wr1 = (const float*)d_in[6];
    const float* Wl2 = (const float*)d_in[7];
    const float* bl2 = (const float*)d_in[8];
    const float* Wr2 = (const float*)d_in[9];
    float* out = (float*)d_out;

    // workspace (~21.2 MB)
    float*        p    = (float*)d_ws;                 // NN*NH
    float*        r    = p + (size_t)NN * NH;          // NN*NH
    float*        q    = r + (size_t)NN * NH;          // NN
    int*          bcnt = (int*)(q + NN);               // NBKT
    unsigned int* bmem = (unsigned int*)(bcnt + NBKT); // NBKT*CAP

    hipMemsetAsync(bcnt, 0, NBKT * sizeof(int), stream);

    k1_node_lin<<<(NN + 255) / 256, 256, 0, stream>>>(x, Wl1, Wr1, p, r);
    k_bucket<<<NBLK_B, 256, 0, stream>>>(ei, As, ws, bcnt, bmem);
    k_agg1<<<NBKT, 256, 0, stream>>>(bcnt, bmem, p, r, bl1, Wl2, bl2, Wr2, q, out);
    k_agg2<<<NBKT, 256, 0, stream>>>(bcnt, bmem, q, out);
}

// Round 4
// 321.054 us; speedup vs baseline: 1.1230x; 1.1230x over previous
//
#include <hip/hip_runtime.h>

constexpr int NN = 100000;   // nodes
constexpr int NE = 1600000;  // edges
constexpr int NF = 64;       // input features
constexpr int NH = 16;       // hidden

constexpr int NPB  = 64;                       // nodes per bucket (dst>>6 / dst&63)
constexpr int LB   = 6;                        // log2(NPB)
constexpr int NBKT = (NN + NPB - 1) / NPB;     // 1563 buckets
constexpr int CAP  = 1280;                     // per-bucket capacity (mean 1024, +8 sigma)
constexpr int CHUNK = 4096;                    // edges per block in bucket build
constexpr int NBLK_B = (NE + CHUNK - 1) / CHUNK; // 391

// Kernel 1: per node n: p[n,:] = x[n,:] @ Wl1 ; r[n,:] = x[n,:] @ Wr1
__global__ __launch_bounds__(256)
void k1_node_lin(const float* __restrict__ x,
                 const float* __restrict__ Wl1,
                 const float* __restrict__ Wr1,
                 float* __restrict__ p,
                 float* __restrict__ r)
{
    __shared__ float sW[2 * NF * NH];
    for (int i = threadIdx.x; i < NF * NH; i += 256) {
        sW[i]           = Wl1[i];
        sW[NF * NH + i] = Wr1[i];
    }
    __syncthreads();

    int n = blockIdx.x * 256 + threadIdx.x;
    if (n >= NN) return;

    float aL[NH], aR[NH];
#pragma unroll
    for (int j = 0; j < NH; ++j) { aL[j] = 0.f; aR[j] = 0.f; }

    const float4* xr = reinterpret_cast<const float4*>(x + (size_t)n * NF);
#pragma unroll
    for (int k4 = 0; k4 < NF / 4; ++k4) {
        float4 v = xr[k4];
        float xs[4] = {v.x, v.y, v.z, v.w};
#pragma unroll
        for (int t = 0; t < 4; ++t) {
            const float* wl = &sW[(k4 * 4 + t) * NH];
            const float* wr = &sW[NF * NH + (k4 * 4 + t) * NH];
#pragma unroll
            for (int j = 0; j < NH; ++j) {
                aL[j] = fmaf(xs[t], wl[j], aL[j]);
                aR[j] = fmaf(xs[t], wr[j], aR[j]);
            }
        }
    }

    float4* pp = reinterpret_cast<float4*>(p + (size_t)n * NH);
    float4* rp = reinterpret_cast<float4*>(r + (size_t)n * NH);
#pragma unroll
    for (int j4 = 0; j4 < NH / 4; ++j4) {
        pp[j4] = make_float4(aL[j4*4], aL[j4*4+1], aL[j4*4+2], aL[j4*4+3]);
        rp[j4] = make_float4(aR[j4*4], aR[j4*4+1], aR[j4*4+2], aR[j4*4+3]);
    }
}

// Bucket build: per-block LDS histogram -> one global reserve per
// (block,bucket) -> sequential tail appends (write-back ~= payload).
__global__ __launch_bounds__(256)
void k_bucket(const int* __restrict__ ei, const float* __restrict__ As,
              const float* __restrict__ ws,
              int* __restrict__ bcnt, unsigned int* __restrict__ bmem)
{
    __shared__ int lcnt[NBKT];
    __shared__ int lbase[NBKT];
    int tid = threadIdx.x;
    for (int i = tid; i < NBKT; i += 256) lcnt[i] = 0;
    __syncthreads();

    int base = blockIdx.x * CHUNK;
    float w0 = ws[0], w1 = ws[1];

    // pass A: count kept edges per bucket (iterations independent -> ILP)
#pragma unroll
    for (int j = 0; j < CHUNK / 256; ++j) {
        int e = base + j * 256 + tid;
        if (e < NE) {
            float ewm = w0 * As[e] + w1 * As[NE + e];
            if (ewm != 0.f)
                atomicAdd(&lcnt[ei[NE + e] >> LB], 1);
        }
    }
    __syncthreads();

    for (int i = tid; i < NBKT; i += 256) {
        int c = lcnt[i];
        lbase[i] = c ? atomicAdd(&bcnt[i], c) : 0;
    }
    __syncthreads();
    for (int i = tid; i < NBKT; i += 256) lcnt[i] = 0;
    __syncthreads();

    // pass B: place (chunk data L2-hot from pass A)
#pragma unroll
    for (int j = 0; j < CHUNK / 256; ++j) {
        int e = base + j * 256 + tid;
        if (e < NE) {
            float ewm = w0 * As[e] + w1 * As[NE + e];
            if (ewm != 0.f) {
                int dst = ei[NE + e];
                int b   = dst >> LB;
                int rank = atomicAdd(&lcnt[b], 1);
                int slot = lbase[b] + rank;
                if (slot < CAP)
                    bmem[(size_t)b * CAP + slot] =
                        ((unsigned)ei[e] << LB) | (unsigned)(dst & (NPB - 1));
            }
        }
    }
}

// Layer-1 aggregation: one block per bucket; LDS accumulator; 16 lanes per
// edge gather one 64B p-line. Software-pipelined 8 edges deep per group.
// Fused epilogue: h = relu(agg + r + bl1); q = h.Wl2; out = h.Wr2 + bl2.
__global__ __launch_bounds__(256)
void k_agg1(const int* __restrict__ bcnt, const unsigned int* __restrict__ bmem,
            const float* __restrict__ p, const float* __restrict__ r,
            const float* __restrict__ bl1, const float* __restrict__ Wl2,
            const float* __restrict__ bl2, const float* __restrict__ Wr2,
            float* __restrict__ q, float* __restrict__ out)
{
    __shared__ float sagg[NPB * NH];   // 4 KB
    int b = blockIdx.x;
    int tid = threadIdx.x;
    for (int i = tid; i < NPB * NH; i += 256) sagg[i] = 0.f;
    __syncthreads();

    int cnt = min(bcnt[b], CAP);
    int grp = tid >> 4, k = tid & 15;
    const unsigned int* bm = bmem + (size_t)b * CAP;

    int i = grp;
    // pipelined main loop: 8 edges in flight per 16-lane group
    for (; i + 7 * 16 < cnt; i += 8 * 16) {
        unsigned v[8];
#pragma unroll
        for (int u = 0; u < 8; ++u) v[u] = bm[i + u * 16];
        float pv[8];
#pragma unroll
        for (int u = 0; u < 8; ++u)
            pv[u] = p[(size_t)(v[u] >> LB) * NH + k];
#pragma unroll
        for (int u = 0; u < 8; ++u)
            atomicAdd(&sagg[(v[u] & (NPB - 1)) * NH + k], pv[u]);
    }
    for (; i < cnt; i += 16) {
        unsigned v = bm[i];
        atomicAdd(&sagg[(v & (NPB - 1)) * NH + k], p[(size_t)(v >> LB) * NH + k]);
    }
    __syncthreads();

    int n0 = b * NPB;
    int nn = min(NPB, NN - n0);
    for (int item = tid; item < nn * NH; item += 256) {
        int l  = item >> 4;
        int kk = item & 15;               // stride 256 preserves lane->kk
        float h = sagg[item] + r[(size_t)(n0 + l) * NH + kk] + bl1[kk];
        h = h > 0.f ? h : 0.f;
        float qv = h * Wl2[kk];
        float sv = h * Wr2[kk];
#pragma unroll
        for (int m = 8; m >= 1; m >>= 1) {
            qv += __shfl_xor(qv, m);
            sv += __shfl_xor(sv, m);
        }
        if (kk == 0) {
            q[n0 + l]   = qv;
            out[n0 + l] = sv + bl2[0];
        }
    }
}

// Layer-2 aggregation: LDS scalar accumulation of q[src], pipelined 4 deep.
__global__ __launch_bounds__(256)
void k_agg2(const int* __restrict__ bcnt, const unsigned int* __restrict__ bmem,
            const float* __restrict__ q, float* __restrict__ out)
{
    __shared__ float sq[NPB];
    int b = blockIdx.x, tid = threadIdx.x;
    if (tid < NPB) sq[tid] = 0.f;
    __syncthreads();

    int cnt = min(bcnt[b], CAP);
    const unsigned int* bm = bmem + (size_t)b * CAP;

    int i = tid;
    for (; i + 3 * 256 < cnt; i += 4 * 256) {
        unsigned v[4];
#pragma unroll
        for (int u = 0; u < 4; ++u) v[u] = bm[i + u * 256];
        float qv[4];
#pragma unroll
        for (int u = 0; u < 4; ++u) qv[u] = q[v[u] >> LB];
#pragma unroll
        for (int u = 0; u < 4; ++u)
            atomicAdd(&sq[v[u] & (NPB - 1)], qv[u]);
    }
    for (; i < cnt; i += 256) {
        unsigned v = bm[i];
        atomicAdd(&sq[v & (NPB - 1)], q[v >> LB]);
    }
    __syncthreads();

    int n0 = b * NPB;
    int nn = min(NPB, NN - n0);
    if (tid < nn) out[n0 + tid] += sq[tid];
}

extern "C" void kernel_launch(void* const* d_in, const int* in_sizes, int n_in,
                              void* d_out, int out_size, void* d_ws, size_t ws_size,
                              hipStream_t stream)
{
    const float* x   = (const float*)d_in[0];
    const int*   ei  = (const int*)  d_in[1];
    const float* As  = (const float*)d_in[2];
    const float* ws  = (const float*)d_in[3];
    const float* Wl1 = (const float*)d_in[4];
    const float* bl1 = (const float*)d_in[5];
    const float* Wr1 = (const float*)d_in[6];
    const float* Wl2 = (const float*)d_in[7];
    const float* bl2 = (const float*)d_in[8];
    const float* Wr2 = (const float*)d_in[9];
    float* out = (float*)d_out;

    // workspace (~21.2 MB)
    float*        p    = (float*)d_ws;                 // NN*NH
    float*        r    = p + (size_t)NN * NH;          // NN*NH
    float*        q    = r + (size_t)NN * NH;          // NN
    int*          bcnt = (int*)(q + NN);               // NBKT
    unsigned int* bmem = (unsigned int*)(bcnt + NBKT); // NBKT*CAP (8.0 MB)

    hipMemsetAsync(bcnt, 0, NBKT * sizeof(int), stream);

    k1_node_lin<<<(NN + 255) / 256, 256, 0, stream>>>(x, Wl1, Wr1, p, r);
    k_bucket<<<NBLK_B, 256, 0, stream>>>(ei, As, ws, bcnt, bmem);
    k_agg1<<<NBKT, 256, 0, stream>>>(bcnt, bmem, p, r, bl1, Wl2, bl2, Wr2, q, out);
    k_agg2<<<NBKT, 256, 0, stream>>>(bcnt, bmem, q, out);
}